// Round 1
// baseline (2857.704 us; speedup 1.0000x reference)
//
#include <hip/hip_runtime.h>

#define NN 100000   // nodes
#define NE 1000000  // edges
#define DD 64       // dim
#define NB 4096     // batch

// ---------------------------------------------------------------------------
// Scatter: side[col] += ego[row] * w  over all edges.
// Wave layout: 4 edges per wave; lane = (edge_sub<<4) | dim_quad.
// Each lane loads a float4 of the source row (16B/lane, 256B per edge,
// coalesced) and issues 4 f32 atomicAdds.
// ---------------------------------------------------------------------------
__global__ __launch_bounds__(256) void k_scatter(
    const float* __restrict__ ego, const float* __restrict__ ew,
    const int* __restrict__ ei, float* __restrict__ side)
{
  const int lane = threadIdx.x & 63;
  const int dq   = lane & 15;   // dim quad 0..15 -> dims 4*dq..4*dq+3
  const int es   = lane >> 4;   // edge sub 0..3
  const int gw = (blockIdx.x * 256 + threadIdx.x) >> 6;
  const int nw = (gridDim.x * 256) >> 6;
  for (int e0 = gw * 4; e0 < NE; e0 += nw * 4) {  // NE % 4 == 0
    const int e = e0 + es;
    const int r = ei[e];
    const int c = ei[NE + e];
    const float w = ew[e];
    const float4 v = *(reinterpret_cast<const float4*>(ego + (size_t)r * DD) + dq);
    float* dst = side + (size_t)c * DD + dq * 4;
    atomicAdd(dst + 0, v.x * w);
    atomicAdd(dst + 1, v.y * w);
    atomicAdd(dst + 2, v.z * w);
    atomicAdd(dst + 3, v.w * w);
  }
}

// ---------------------------------------------------------------------------
// Fused per-node update: one wave per node (lane = dim).
//   x   = side@Wgc + bgc + (ego .* side)@Wbi + bbi
//   ego' = leaky_relu(x, 0.2)            (written to ego_out)
//   norm = ego' / max(||ego'||_2, 1e-12) (written to normed)
// W columns live in VGPRs (lane d holds W[:, d]); the K-broadcast uses
// v_readlane (SGPR result) feeding v_fmac — no LDS, no shuffles in the
// inner loop. 128 FMA + 128 readlane per node.
// ---------------------------------------------------------------------------
__global__ __launch_bounds__(256) void k_update(
    const float* __restrict__ side, const float* __restrict__ ego_in,
    float* __restrict__ ego_out, float* __restrict__ normed,
    const float* __restrict__ Wgc, const float* __restrict__ bgc,
    const float* __restrict__ Wbi, const float* __restrict__ bbi)
{
  const int lane = threadIdx.x & 63;
  float wg[DD], wb[DD];
#pragma unroll
  for (int j = 0; j < DD; ++j) {
    wg[j] = Wgc[j * DD + lane];   // lane d holds column d of W
    wb[j] = Wbi[j * DD + lane];
  }
  const float bias = bgc[lane] + bbi[lane];
  const int gw = (blockIdx.x * 256 + threadIdx.x) >> 6;
  const int nw = (gridDim.x * 256) >> 6;
  for (int n = gw; n < NN; n += nw) {
    const float s = side[(size_t)n * DD + lane];
    const float e = ego_in[(size_t)n * DD + lane];
    const float p = s * e;
    float ag = 0.f, ab = 0.f;
#pragma unroll
    for (int j = 0; j < DD; ++j) {
      const float sj = __uint_as_float(__builtin_amdgcn_readlane(__float_as_uint(s), j));
      const float pj = __uint_as_float(__builtin_amdgcn_readlane(__float_as_uint(p), j));
      ag = fmaf(sj, wg[j], ag);
      ab = fmaf(pj, wb[j], ab);
    }
    float x = ag + ab + bias;
    x = (x > 0.f) ? x : 0.2f * x;               // leaky_relu(0.2)
    ego_out[(size_t)n * DD + lane] = x;
    float ss = x * x;
#pragma unroll
    for (int off = 32; off >= 1; off >>= 1) ss += __shfl_xor(ss, off);
    const float nrm = fmaxf(sqrtf(ss), 1e-12f);
    normed[(size_t)n * DD + lane] = x / nrm;
  }
}

// ---------------------------------------------------------------------------
// Gather sampled rows (users/pos/neg) of a 64-wide source into the [*,256]
// output at column offset colOff; duplicated into the second triple.
// One wave per (which, i); lane = column within the 64-block.
// ---------------------------------------------------------------------------
__global__ __launch_bounds__(256) void k_gather(
    const float* __restrict__ src, const int* __restrict__ users,
    const int* __restrict__ pos, const int* __restrict__ neg,
    float* __restrict__ out, int colOff)
{
  const int w = (blockIdx.x * 256 + threadIdx.x) >> 6;
  const int lane = threadIdx.x & 63;
  if (w >= 3 * NB) return;
  const int t = w / NB;
  const int i = w - t * NB;
  const int* idxp = (t == 0) ? users : ((t == 1) ? pos : neg);
  const int idx = idxp[i];
  const float v = src[(size_t)idx * DD + lane];
  const size_t o = (size_t)w * 256 + colOff + lane;
  out[o] = v;
  out[o + (size_t)3 * NB * 256] = v;  // outputs are duplicated in return tuple
}

extern "C" void kernel_launch(void* const* d_in, const int* in_sizes, int n_in,
                              void* d_out, int out_size, void* d_ws, size_t ws_size,
                              hipStream_t stream)
{
  const float* embeds = (const float*)d_in[0];
  const float* ew     = (const float*)d_in[1];
  const float* Wgc    = (const float*)d_in[2];
  const float* bgc    = (const float*)d_in[3];
  const float* Wbi    = (const float*)d_in[4];
  const float* bbi    = (const float*)d_in[5];
  const int*   ei     = (const int*)d_in[6];
  const int*   users  = (const int*)d_in[7];
  const int*   pos    = (const int*)d_in[8];
  const int*   neg    = (const int*)d_in[9];
  float* out  = (float*)d_out;

  float* side = (float*)d_ws;                    // [NN, 64]
  float* ego  = side + (size_t)NN * DD;          // [NN, 64]
  float* norm = ego  + (size_t)NN * DD;          // [NN, 64]

  const dim3 blk(256);

  // column block 0: raw embeds rows
  k_gather<<<dim3((3 * NB) / 4), blk, 0, stream>>>(embeds, users, pos, neg, out, 0);

  const float* cur = embeds;
  for (int k = 0; k < 3; ++k) {
    hipMemsetAsync(side, 0, (size_t)NN * DD * sizeof(float), stream);
    k_scatter<<<dim3(4096), blk, 0, stream>>>(cur, ew, ei, side);
    k_update<<<dim3(1024), blk, 0, stream>>>(
        side, cur, ego, norm,
        Wgc + (size_t)k * DD * DD, bgc + (size_t)k * DD,
        Wbi + (size_t)k * DD * DD, bbi + (size_t)k * DD);
    k_gather<<<dim3((3 * NB) / 4), blk, 0, stream>>>(norm, users, pos, neg, out,
                                                     DD * (k + 1));
    cur = ego;
  }
}

// Round 4
// 827.337 us; speedup vs baseline: 3.4541x; 3.4541x over previous
//
#include <hip/hip_runtime.h>

#define NN 100000   // nodes
#define NE 1000000  // edges
#define DD 64       // dim
#define NB 4096     // batch
#define SCAN_T 1024

// ---------------------------------------------------------------------------
// CSR build step 1: count edges per destination node. base[c]++ (int atomics).
// ---------------------------------------------------------------------------
__global__ __launch_bounds__(256) void k_count(
    const int* __restrict__ ei, int* __restrict__ base)
{
  const int stride = gridDim.x * blockDim.x;
  for (int e = blockIdx.x * blockDim.x + threadIdx.x; e < NE; e += stride)
    atomicAdd(&base[ei[NE + e]], 1);
}

// ---------------------------------------------------------------------------
// CSR build step 2: single-block exclusive scan of base[0..NN) -> base, cursor.
// 1024 threads, each owns a contiguous chunk; Hillis-Steele scan in LDS.
// Also writes base[NN] = NE.
// ---------------------------------------------------------------------------
__global__ __launch_bounds__(SCAN_T) void k_scan(
    int* __restrict__ base, int* __restrict__ cursor)
{
  __shared__ int s[SCAN_T];
  const int t = threadIdx.x;
  const int chunk = (NN + SCAN_T - 1) / SCAN_T;
  const int lo = t * chunk;
  const int hi = min(lo + chunk, NN);
  int sum = 0;
  for (int i = lo; i < hi; ++i) sum += base[i];
  s[t] = sum;
  __syncthreads();
  for (int off = 1; off < SCAN_T; off <<= 1) {
    int v = (t >= off) ? s[t - off] : 0;
    __syncthreads();
    s[t] += v;
    __syncthreads();
  }
  int running = s[t] - sum;  // exclusive prefix of this chunk
  for (int i = lo; i < hi; ++i) {
    int c = base[i];
    base[i] = running;
    cursor[i] = running;
    running += c;
  }
  if (t == SCAN_T - 1) base[NN] = s[SCAN_T - 1];
}

// ---------------------------------------------------------------------------
// CSR build step 3: bucket edges by destination. edata[slot] = (row, w).
// ---------------------------------------------------------------------------
__global__ __launch_bounds__(256) void k_permute(
    const int* __restrict__ ei, const float* __restrict__ ew,
    int* __restrict__ cursor, int2* __restrict__ edata)
{
  const int stride = gridDim.x * blockDim.x;
  for (int e = blockIdx.x * blockDim.x + threadIdx.x; e < NE; e += stride) {
    const int c = ei[NE + e];
    const int slot = atomicAdd(&cursor[c], 1);
    edata[slot] = make_int2(ei[e], __float_as_int(ew[e]));
  }
}

// ---------------------------------------------------------------------------
// Aggregation without atomics: one wave per node, lane = dim.
//   side[n,:] = sum over incident edges of ego[row]*w
// Every element written (0 for degree-0 nodes) -> no memset needed.
// ---------------------------------------------------------------------------
__global__ __launch_bounds__(256) void k_aggregate(
    const float* __restrict__ ego, const int* __restrict__ base,
    const int2* __restrict__ edata, float* __restrict__ side)
{
  const int lane = threadIdx.x & 63;
  const int gw = (blockIdx.x * 256 + threadIdx.x) >> 6;
  const int nw = (gridDim.x * 256) >> 6;
  for (int n = gw; n < NN; n += nw) {
    const int lo = base[n];
    const int hi = base[n + 1];
    float acc = 0.f;
    int j = lo;
    for (; j + 1 < hi; j += 2) {          // unroll-2 for load ILP
      const int2 a = edata[j];
      const int2 b = edata[j + 1];
      const float va = ego[(size_t)a.x * DD + lane];
      const float vb = ego[(size_t)b.x * DD + lane];
      acc = fmaf(va, __int_as_float(a.y), acc);
      acc = fmaf(vb, __int_as_float(b.y), acc);
    }
    if (j < hi) {
      const int2 a = edata[j];
      acc = fmaf(ego[(size_t)a.x * DD + lane], __int_as_float(a.y), acc);
    }
    side[(size_t)n * DD + lane] = acc;
  }
}

// ---------------------------------------------------------------------------
// Fallback scatter (atomics) if ws_size is too small for CSR.
// ---------------------------------------------------------------------------
__global__ __launch_bounds__(256) void k_scatter(
    const float* __restrict__ ego, const float* __restrict__ ew,
    const int* __restrict__ ei, float* __restrict__ side)
{
  const int lane = threadIdx.x & 63;
  const int dq = lane & 15;
  const int es = lane >> 4;
  const int gw = (blockIdx.x * 256 + threadIdx.x) >> 6;
  const int nw = (gridDim.x * 256) >> 6;
  for (int e0 = gw * 4; e0 < NE; e0 += nw * 4) {
    const int e = e0 + es;
    const int r = ei[e];
    const int c = ei[NE + e];
    const float w = ew[e];
    const float4 v = *(reinterpret_cast<const float4*>(ego + (size_t)r * DD) + dq);
    float* dst = side + (size_t)c * DD + dq * 4;
    atomicAdd(dst + 0, v.x * w);
    atomicAdd(dst + 1, v.y * w);
    atomicAdd(dst + 2, v.z * w);
    atomicAdd(dst + 3, v.w * w);
  }
}

// ---------------------------------------------------------------------------
// Fused per-node dense update: one wave per node (lane = dim).
//   x = side@Wgc + bgc + (ego .* side)@Wbi + bbi ; leaky_relu ; l2-normalize
// W columns in VGPRs; K-broadcast via v_readlane feeding v_fmac.
// ---------------------------------------------------------------------------
__global__ __launch_bounds__(256) void k_update(
    const float* __restrict__ side, const float* __restrict__ ego_in,
    float* __restrict__ ego_out, float* __restrict__ normed,
    const float* __restrict__ Wgc, const float* __restrict__ bgc,
    const float* __restrict__ Wbi, const float* __restrict__ bbi)
{
  const int lane = threadIdx.x & 63;
  float wg[DD], wb[DD];
#pragma unroll
  for (int j = 0; j < DD; ++j) {
    wg[j] = Wgc[j * DD + lane];
    wb[j] = Wbi[j * DD + lane];
  }
  const float bias = bgc[lane] + bbi[lane];
  const int gw = (blockIdx.x * 256 + threadIdx.x) >> 6;
  const int nw = (gridDim.x * 256) >> 6;
  for (int n = gw; n < NN; n += nw) {
    const float s = side[(size_t)n * DD + lane];
    const float e = ego_in[(size_t)n * DD + lane];
    const float p = s * e;
    float ag = 0.f, ab = 0.f;
#pragma unroll
    for (int j = 0; j < DD; ++j) {
      const float sj = __uint_as_float(__builtin_amdgcn_readlane(__float_as_uint(s), j));
      const float pj = __uint_as_float(__builtin_amdgcn_readlane(__float_as_uint(p), j));
      ag = fmaf(sj, wg[j], ag);
      ab = fmaf(pj, wb[j], ab);
    }
    float x = ag + ab + bias;
    x = (x > 0.f) ? x : 0.2f * x;
    ego_out[(size_t)n * DD + lane] = x;
    float ss = x * x;
#pragma unroll
    for (int off = 32; off >= 1; off >>= 1) ss += __shfl_xor(ss, off);
    const float nrm = fmaxf(sqrtf(ss), 1e-12f);
    normed[(size_t)n * DD + lane] = x / nrm;
  }
}

// ---------------------------------------------------------------------------
// Gather sampled rows into the [*,256] outputs (duplicated second triple).
// ---------------------------------------------------------------------------
__global__ __launch_bounds__(256) void k_gather(
    const float* __restrict__ src, const int* __restrict__ users,
    const int* __restrict__ pos, const int* __restrict__ neg,
    float* __restrict__ out, int colOff)
{
  const int w = (blockIdx.x * 256 + threadIdx.x) >> 6;
  const int lane = threadIdx.x & 63;
  if (w >= 3 * NB) return;
  const int t = w / NB;
  const int i = w - t * NB;
  const int* idxp = (t == 0) ? users : ((t == 1) ? pos : neg);
  const int idx = idxp[i];
  const float v = src[(size_t)idx * DD + lane];
  const size_t o = (size_t)w * 256 + colOff + lane;
  out[o] = v;
  out[o + (size_t)3 * NB * 256] = v;
}

extern "C" void kernel_launch(void* const* d_in, const int* in_sizes, int n_in,
                              void* d_out, int out_size, void* d_ws, size_t ws_size,
                              hipStream_t stream)
{
  const float* embeds = (const float*)d_in[0];
  const float* ew     = (const float*)d_in[1];
  const float* Wgc    = (const float*)d_in[2];
  const float* bgc    = (const float*)d_in[3];
  const float* Wbi    = (const float*)d_in[4];
  const float* bbi    = (const float*)d_in[5];
  const int*   ei     = (const int*)d_in[6];
  const int*   users  = (const int*)d_in[7];
  const int*   pos    = (const int*)d_in[8];
  const int*   neg    = (const int*)d_in[9];
  float* out = (float*)d_out;

  // Workspace layout (4B units); big arrays first, 8B alignment for edata.
  float* side = (float*)d_ws;                    // NN*DD
  float* ego  = side + (size_t)NN * DD;          // NN*DD
  float* norm = ego  + (size_t)NN * DD;          // NN*DD
  int*   base   = (int*)(norm + (size_t)NN * DD);// NN+2 (pad to even)
  int*   cursor = base + (NN + 2);               // NN
  int2*  edata  = (int2*)(cursor + NN);          // NE int2
  const size_t need = ((size_t)3 * NN * DD + (NN + 2) + NN) * 4 + (size_t)NE * 8;

  const dim3 blk(256);
  const bool csr = ws_size >= need;

  k_gather<<<dim3((3 * NB) / 4), blk, 0, stream>>>(embeds, users, pos, neg, out, 0);

  if (csr) {
    hipMemsetAsync(base, 0, (size_t)(NN + 2) * sizeof(int), stream);
    k_count<<<dim3(1024), blk, 0, stream>>>(ei, base);
    k_scan<<<dim3(1), dim3(SCAN_T), 0, stream>>>(base, cursor);
    k_permute<<<dim3(1024), blk, 0, stream>>>(ei, ew, cursor, edata);
  }

  const float* cur = embeds;
  for (int k = 0; k < 3; ++k) {
    if (csr) {
      k_aggregate<<<dim3(4096), blk, 0, stream>>>(cur, base, edata, side);
    } else {
      hipMemsetAsync(side, 0, (size_t)NN * DD * sizeof(float), stream);
      k_scatter<<<dim3(4096), blk, 0, stream>>>(cur, ew, ei, side);
    }
    k_update<<<dim3(1024), blk, 0, stream>>>(
        side, cur, ego, norm,
        Wgc + (size_t)k * DD * DD, bgc + (size_t)k * DD,
        Wbi + (size_t)k * DD * DD, bbi + (size_t)k * DD);
    k_gather<<<dim3((3 * NB) / 4), blk, 0, stream>>>(norm, users, pos, neg, out,
                                                     DD * (k + 1));
    cur = ego;
  }
}

// Round 5
// 603.855 us; speedup vs baseline: 4.7324x; 1.3701x over previous
//
#include <hip/hip_runtime.h>

#define NN 100000   // nodes
#define NE 1000000  // edges
#define DD 64       // dim
#define NB 4096     // batch
#define TILE 1024                       // scan tile (ints per block)
#define NTILE ((NN + TILE - 1) / TILE)  // 98

// ---------------------------------------------------------------------------
// CSR build step 1: count edges per destination node. base[c]++ (int atomics).
// ---------------------------------------------------------------------------
__global__ __launch_bounds__(256) void k_count(
    const int* __restrict__ ei, int* __restrict__ base)
{
  const int stride = gridDim.x * blockDim.x;
  for (int e = blockIdx.x * blockDim.x + threadIdx.x; e < NE; e += stride)
    atomicAdd(&base[ei[NE + e]], 1);
}

// ---------------------------------------------------------------------------
// Hierarchical exclusive scan of base[0..NN) (3 kernels, coalesced int4).
// step A: per-tile sums (98 tiles x 1024 ints, 256 thr x int4 each).
// ---------------------------------------------------------------------------
__global__ __launch_bounds__(256) void k_scan_part(
    const int* __restrict__ base, int* __restrict__ tilesum)
{
  __shared__ int s[256];
  const int t = threadIdx.x;
  const int i0 = blockIdx.x * TILE + t * 4;
  int4 v = make_int4(0, 0, 0, 0);
  if (i0 < NN) v = *reinterpret_cast<const int4*>(base + i0);  // NN%4==0
  s[t] = v.x + v.y + v.z + v.w;
  __syncthreads();
#pragma unroll
  for (int off = 128; off >= 1; off >>= 1) {
    if (t < off) s[t] += s[t + off];
    __syncthreads();
  }
  if (t == 0) tilesum[blockIdx.x] = s[0];
}

// step B: exclusive scan of the 98 tile sums (single tiny block).
__global__ __launch_bounds__(128) void k_scan_tiles(
    const int* __restrict__ tilesum, int* __restrict__ tileoff)
{
  __shared__ int s[128];
  const int t = threadIdx.x;
  const int v = (t < NTILE) ? tilesum[t] : 0;
  s[t] = v;
  __syncthreads();
#pragma unroll
  for (int off = 1; off < 128; off <<= 1) {
    const int u = (t >= off) ? s[t - off] : 0;
    __syncthreads();
    s[t] += u;
    __syncthreads();
  }
  if (t < NTILE) tileoff[t] = s[t] - v;  // exclusive
}

// step C: per-tile exclusive scan + tile offset; write base & cursor in place.
__global__ __launch_bounds__(256) void k_scan_apply(
    int* __restrict__ base, int* __restrict__ cursor,
    const int* __restrict__ tileoff)
{
  __shared__ int s[256];
  const int t = threadIdx.x;
  const int i0 = blockIdx.x * TILE + t * 4;
  int4 v = make_int4(0, 0, 0, 0);
  if (i0 < NN) v = *reinterpret_cast<const int4*>(base + i0);
  const int sum = v.x + v.y + v.z + v.w;
  s[t] = sum;
  __syncthreads();
#pragma unroll
  for (int off = 1; off < 256; off <<= 1) {   // Hillis-Steele inclusive
    const int u = (t >= off) ? s[t - off] : 0;
    __syncthreads();
    s[t] += u;
    __syncthreads();
  }
  int p = s[t] - sum + tileoff[blockIdx.x];   // exclusive prefix of this int4
  if (i0 < NN) {
    const int4 o = make_int4(p, p + v.x, p + v.x + v.y, p + v.x + v.y + v.z);
    *reinterpret_cast<int4*>(base + i0) = o;
    *reinterpret_cast<int4*>(cursor + i0) = o;
  }
  if (blockIdx.x == 0 && t == 0) base[NN] = NE;
}

// ---------------------------------------------------------------------------
// CSR build step 3: bucket edges by destination. edata[slot] = (row, w).
// ---------------------------------------------------------------------------
__global__ __launch_bounds__(256) void k_permute(
    const int* __restrict__ ei, const float* __restrict__ ew,
    int* __restrict__ cursor, int2* __restrict__ edata)
{
  const int stride = gridDim.x * blockDim.x;
  for (int e = blockIdx.x * blockDim.x + threadIdx.x; e < NE; e += stride) {
    const int c = ei[NE + e];
    const int slot = atomicAdd(&cursor[c], 1);
    edata[slot] = make_int2(ei[e], __float_as_int(ew[e]));
  }
}

// ---------------------------------------------------------------------------
// Aggregation without atomics: one wave per node, lane = dim.
//   side[n,:] = sum over incident edges of ego[row]*w
// ---------------------------------------------------------------------------
__global__ __launch_bounds__(256) void k_aggregate(
    const float* __restrict__ ego, const int* __restrict__ base,
    const int2* __restrict__ edata, float* __restrict__ side)
{
  const int lane = threadIdx.x & 63;
  const int gw = (blockIdx.x * 256 + threadIdx.x) >> 6;
  const int nw = (gridDim.x * 256) >> 6;
  for (int n = gw; n < NN; n += nw) {
    const int lo = base[n];
    const int hi = base[n + 1];
    float acc = 0.f;
    int j = lo;
    for (; j + 1 < hi; j += 2) {          // unroll-2 for load ILP
      const int2 a = edata[j];
      const int2 b = edata[j + 1];
      const float va = ego[(size_t)a.x * DD + lane];
      const float vb = ego[(size_t)b.x * DD + lane];
      acc = fmaf(va, __int_as_float(a.y), acc);
      acc = fmaf(vb, __int_as_float(b.y), acc);
    }
    if (j < hi) {
      const int2 a = edata[j];
      acc = fmaf(ego[(size_t)a.x * DD + lane], __int_as_float(a.y), acc);
    }
    side[(size_t)n * DD + lane] = acc;
  }
}

// ---------------------------------------------------------------------------
// Fused per-node dense update: one wave per node (lane = dim).
//   x = side@Wgc + bgc + (ego .* side)@Wbi + bbi ; leaky_relu ; l2-normalize
// W columns in VGPRs; K-broadcast via v_readlane feeding v_fmac.
// ---------------------------------------------------------------------------
__global__ __launch_bounds__(256) void k_update(
    const float* __restrict__ side, const float* __restrict__ ego_in,
    float* __restrict__ ego_out, float* __restrict__ normed,
    const float* __restrict__ Wgc, const float* __restrict__ bgc,
    const float* __restrict__ Wbi, const float* __restrict__ bbi)
{
  const int lane = threadIdx.x & 63;
  float wg[DD], wb[DD];
#pragma unroll
  for (int j = 0; j < DD; ++j) {
    wg[j] = Wgc[j * DD + lane];
    wb[j] = Wbi[j * DD + lane];
  }
  const float bias = bgc[lane] + bbi[lane];
  const int gw = (blockIdx.x * 256 + threadIdx.x) >> 6;
  const int nw = (gridDim.x * 256) >> 6;
  for (int n = gw; n < NN; n += nw) {
    const float s = side[(size_t)n * DD + lane];
    const float e = ego_in[(size_t)n * DD + lane];
    const float p = s * e;
    float ag = 0.f, ab = 0.f;
#pragma unroll
    for (int j = 0; j < DD; ++j) {
      const float sj = __uint_as_float(__builtin_amdgcn_readlane(__float_as_uint(s), j));
      const float pj = __uint_as_float(__builtin_amdgcn_readlane(__float_as_uint(p), j));
      ag = fmaf(sj, wg[j], ag);
      ab = fmaf(pj, wb[j], ab);
    }
    float x = ag + ab + bias;
    x = (x > 0.f) ? x : 0.2f * x;
    ego_out[(size_t)n * DD + lane] = x;
    float ss = x * x;
#pragma unroll
    for (int off = 32; off >= 1; off >>= 1) ss += __shfl_xor(ss, off);
    const float nrm = fmaxf(sqrtf(ss), 1e-12f);
    normed[(size_t)n * DD + lane] = x / nrm;
  }
}

// ---------------------------------------------------------------------------
// Gather sampled rows into the [*,256] outputs (duplicated second triple).
// ---------------------------------------------------------------------------
__global__ __launch_bounds__(256) void k_gather(
    const float* __restrict__ src, const int* __restrict__ users,
    const int* __restrict__ pos, const int* __restrict__ neg,
    float* __restrict__ out, int colOff)
{
  const int w = (blockIdx.x * 256 + threadIdx.x) >> 6;
  const int lane = threadIdx.x & 63;
  if (w >= 3 * NB) return;
  const int t = w / NB;
  const int i = w - t * NB;
  const int* idxp = (t == 0) ? users : ((t == 1) ? pos : neg);
  const int idx = idxp[i];
  const float v = src[(size_t)idx * DD + lane];
  const size_t o = (size_t)w * 256 + colOff + lane;
  out[o] = v;
  out[o + (size_t)3 * NB * 256] = v;
}

extern "C" void kernel_launch(void* const* d_in, const int* in_sizes, int n_in,
                              void* d_out, int out_size, void* d_ws, size_t ws_size,
                              hipStream_t stream)
{
  const float* embeds = (const float*)d_in[0];
  const float* ew     = (const float*)d_in[1];
  const float* Wgc    = (const float*)d_in[2];
  const float* bgc    = (const float*)d_in[3];
  const float* Wbi    = (const float*)d_in[4];
  const float* bbi    = (const float*)d_in[5];
  const int*   ei     = (const int*)d_in[6];
  const int*   users  = (const int*)d_in[7];
  const int*   pos    = (const int*)d_in[8];
  const int*   neg    = (const int*)d_in[9];
  float* out = (float*)d_out;

  // Workspace layout (4B units); 16B alignment holds for all int4 accesses.
  float* side = (float*)d_ws;                     // NN*DD
  float* ego  = side + (size_t)NN * DD;           // NN*DD
  float* norm = ego  + (size_t)NN * DD;           // NN*DD
  int*   base   = (int*)(norm + (size_t)NN * DD); // NN+4 (pad)
  int*   cursor = base + (NN + 4);                // NN
  int*   tiles  = cursor + NN;                    // NTILE sums + NTILE offs
  int2*  edata  = (int2*)(tiles + 2 * ((NTILE + 1) & ~1)); // NE int2

  const dim3 blk(256);

  k_gather<<<dim3((3 * NB) / 4), blk, 0, stream>>>(embeds, users, pos, neg, out, 0);

  // CSR build
  hipMemsetAsync(base, 0, (size_t)(NN + 4) * sizeof(int), stream);
  k_count<<<dim3(1024), blk, 0, stream>>>(ei, base);
  k_scan_part<<<dim3(NTILE), blk, 0, stream>>>(base, tiles);
  k_scan_tiles<<<dim3(1), dim3(128), 0, stream>>>(tiles, tiles + ((NTILE + 1) & ~1));
  k_scan_apply<<<dim3(NTILE), blk, 0, stream>>>(base, cursor, tiles + ((NTILE + 1) & ~1));
  k_permute<<<dim3(1024), blk, 0, stream>>>(ei, ew, cursor, edata);

  const float* cur = embeds;
  for (int k = 0; k < 3; ++k) {
    k_aggregate<<<dim3(4096), blk, 0, stream>>>(cur, base, edata, side);
    k_update<<<dim3(1024), blk, 0, stream>>>(
        side, cur, ego, norm,
        Wgc + (size_t)k * DD * DD, bgc + (size_t)k * DD,
        Wbi + (size_t)k * DD * DD, bbi + (size_t)k * DD);
    k_gather<<<dim3((3 * NB) / 4), blk, 0, stream>>>(norm, users, pos, neg, out,
                                                     DD * (k + 1));
    cur = ego;
  }
}

// Round 7
// 489.947 us; speedup vs baseline: 5.8327x; 1.2325x over previous
//
#include <hip/hip_runtime.h>

#define NN 100000   // nodes
#define NE 1000000  // edges
#define DD 64       // dim
#define NB 4096     // batch
#define TILE 1024                       // scan tile (ints per block)
#define NTILE ((NN + TILE - 1) / TILE)  // 98

// ---------------------------------------------------------------------------
// CSR build step 1: count edges per destination AND record each edge's rank
// within its bucket (the atomic's return value). rank is stored coalesced.
// ---------------------------------------------------------------------------
__global__ __launch_bounds__(256) void k_count(
    const int* __restrict__ ei, int* __restrict__ base, int* __restrict__ rank)
{
  const int stride = gridDim.x * blockDim.x;
  for (int e = blockIdx.x * blockDim.x + threadIdx.x; e < NE; e += stride)
    rank[e] = atomicAdd(&base[ei[NE + e]], 1);
}

// ---------------------------------------------------------------------------
// Hierarchical exclusive scan of base[0..NN) (3 kernels, coalesced int4).
// step A: per-tile sums (98 tiles x 1024 ints, 256 thr x int4 each).
// ---------------------------------------------------------------------------
__global__ __launch_bounds__(256) void k_scan_part(
    const int* __restrict__ base, int* __restrict__ tilesum)
{
  __shared__ int s[256];
  const int t = threadIdx.x;
  const int i0 = blockIdx.x * TILE + t * 4;
  int4 v = make_int4(0, 0, 0, 0);
  if (i0 < NN) v = *reinterpret_cast<const int4*>(base + i0);  // NN%4==0
  s[t] = v.x + v.y + v.z + v.w;
  __syncthreads();
#pragma unroll
  for (int off = 128; off >= 1; off >>= 1) {
    if (t < off) s[t] += s[t + off];
    __syncthreads();
  }
  if (t == 0) tilesum[blockIdx.x] = s[0];
}

// step B: exclusive scan of the 98 tile sums (single tiny block).
__global__ __launch_bounds__(128) void k_scan_tiles(
    const int* __restrict__ tilesum, int* __restrict__ tileoff)
{
  __shared__ int s[128];
  const int t = threadIdx.x;
  const int v = (t < NTILE) ? tilesum[t] : 0;
  s[t] = v;
  __syncthreads();
#pragma unroll
  for (int off = 1; off < 128; off <<= 1) {
    const int u = (t >= off) ? s[t - off] : 0;
    __syncthreads();
    s[t] += u;
    __syncthreads();
  }
  if (t < NTILE) tileoff[t] = s[t] - v;  // exclusive
}

// step C: per-tile exclusive scan + tile offset; write base in place.
__global__ __launch_bounds__(256) void k_scan_apply(
    int* __restrict__ base, const int* __restrict__ tileoff)
{
  __shared__ int s[256];
  const int t = threadIdx.x;
  const int i0 = blockIdx.x * TILE + t * 4;
  int4 v = make_int4(0, 0, 0, 0);
  if (i0 < NN) v = *reinterpret_cast<const int4*>(base + i0);
  const int sum = v.x + v.y + v.z + v.w;
  s[t] = sum;
  __syncthreads();
#pragma unroll
  for (int off = 1; off < 256; off <<= 1) {   // Hillis-Steele inclusive
    const int u = (t >= off) ? s[t - off] : 0;
    __syncthreads();
    s[t] += u;
    __syncthreads();
  }
  int p = s[t] - sum + tileoff[blockIdx.x];   // exclusive prefix of this int4
  if (i0 < NN) {
    const int4 o = make_int4(p, p + v.x, p + v.x + v.y, p + v.x + v.y + v.z);
    *reinterpret_cast<int4*>(base + i0) = o;
  }
  if (blockIdx.x == 0 && t == 0) base[NN] = NE;
}

// ---------------------------------------------------------------------------
// CSR build step 3: bucket edges by destination, atomic-free.
//   slot = base[c] + rank[e];  edata[slot] = (row, w)
// ---------------------------------------------------------------------------
__global__ __launch_bounds__(256) void k_permute(
    const int* __restrict__ ei, const float* __restrict__ ew,
    const int* __restrict__ base, const int* __restrict__ rank,
    int2* __restrict__ edata)
{
  const int stride = gridDim.x * blockDim.x;
  for (int e = blockIdx.x * blockDim.x + threadIdx.x; e < NE; e += stride) {
    const int c = ei[NE + e];
    const int slot = base[c] + rank[e];
    edata[slot] = make_int2(ei[e], __float_as_int(ew[e]));
  }
}

// ---------------------------------------------------------------------------
// Aggregation without atomics: one wave per node, lane = dim.
//   side[n,:] = sum over incident edges of ego[row]*w
// ---------------------------------------------------------------------------
__global__ __launch_bounds__(256) void k_aggregate(
    const float* __restrict__ ego, const int* __restrict__ base,
    const int2* __restrict__ edata, float* __restrict__ side)
{
  const int lane = threadIdx.x & 63;
  const int gw = (blockIdx.x * 256 + threadIdx.x) >> 6;
  const int nw = (gridDim.x * 256) >> 6;
  for (int n = gw; n < NN; n += nw) {
    const int lo = base[n];
    const int hi = base[n + 1];
    float acc = 0.f;
    int j = lo;
    for (; j + 3 < hi; j += 4) {          // unroll-4 for load ILP
      const int2 a = edata[j];
      const int2 b = edata[j + 1];
      const int2 c = edata[j + 2];
      const int2 d = edata[j + 3];
      const float va = ego[(size_t)a.x * DD + lane];
      const float vb = ego[(size_t)b.x * DD + lane];
      const float vc = ego[(size_t)c.x * DD + lane];
      const float vd = ego[(size_t)d.x * DD + lane];
      acc = fmaf(va, __int_as_float(a.y), acc);
      acc = fmaf(vb, __int_as_float(b.y), acc);
      acc = fmaf(vc, __int_as_float(c.y), acc);
      acc = fmaf(vd, __int_as_float(d.y), acc);
    }
    for (; j < hi; ++j) {
      const int2 a = edata[j];
      acc = fmaf(ego[(size_t)a.x * DD + lane], __int_as_float(a.y), acc);
    }
    side[(size_t)n * DD + lane] = acc;
  }
}

// ---------------------------------------------------------------------------
// Fused per-node dense update: one wave per node (lane = dim).
//   x = side@Wgc + bgc + (ego .* side)@Wbi + bbi ; leaky_relu ; l2-normalize
// W columns in VGPRs; K-broadcast via v_readlane feeding v_fmac.
// ---------------------------------------------------------------------------
__global__ __launch_bounds__(256) void k_update(
    const float* __restrict__ side, const float* __restrict__ ego_in,
    float* __restrict__ ego_out, float* __restrict__ normed,
    const float* __restrict__ Wgc, const float* __restrict__ bgc,
    const float* __restrict__ Wbi, const float* __restrict__ bbi)
{
  const int lane = threadIdx.x & 63;
  float wg[DD], wb[DD];
#pragma unroll
  for (int j = 0; j < DD; ++j) {
    wg[j] = Wgc[j * DD + lane];
    wb[j] = Wbi[j * DD + lane];
  }
  const float bias = bgc[lane] + bbi[lane];
  const int gw = (blockIdx.x * 256 + threadIdx.x) >> 6;
  const int nw = (gridDim.x * 256) >> 6;
  for (int n = gw; n < NN; n += nw) {
    const float s = side[(size_t)n * DD + lane];
    const float e = ego_in[(size_t)n * DD + lane];
    const float p = s * e;
    float ag = 0.f, ab = 0.f;
#pragma unroll
    for (int j = 0; j < DD; ++j) {
      const float sj = __uint_as_float(__builtin_amdgcn_readlane(__float_as_uint(s), j));
      const float pj = __uint_as_float(__builtin_amdgcn_readlane(__float_as_uint(p), j));
      ag = fmaf(sj, wg[j], ag);
      ab = fmaf(pj, wb[j], ab);
    }
    float x = ag + ab + bias;
    x = (x > 0.f) ? x : 0.2f * x;
    ego_out[(size_t)n * DD + lane] = x;
    float ss = x * x;
#pragma unroll
    for (int off = 32; off >= 1; off >>= 1) ss += __shfl_xor(ss, off);
    const float nrm = fmaxf(sqrtf(ss), 1e-12f);
    normed[(size_t)n * DD + lane] = x / nrm;
  }
}

// ---------------------------------------------------------------------------
// Gather sampled rows into the [*,256] outputs (duplicated second triple).
// ---------------------------------------------------------------------------
__global__ __launch_bounds__(256) void k_gather(
    const float* __restrict__ src, const int* __restrict__ users,
    const int* __restrict__ pos, const int* __restrict__ neg,
    float* __restrict__ out, int colOff)
{
  const int w = (blockIdx.x * 256 + threadIdx.x) >> 6;
  const int lane = threadIdx.x & 63;
  if (w >= 3 * NB) return;
  const int t = w / NB;
  const int i = w - t * NB;
  const int* idxp = (t == 0) ? users : ((t == 1) ? pos : neg);
  const int idx = idxp[i];
  const float v = src[(size_t)idx * DD + lane];
  const size_t o = (size_t)w * 256 + colOff + lane;
  out[o] = v;
  out[o + (size_t)3 * NB * 256] = v;
}

extern "C" void kernel_launch(void* const* d_in, const int* in_sizes, int n_in,
                              void* d_out, int out_size, void* d_ws, size_t ws_size,
                              hipStream_t stream)
{
  const float* embeds = (const float*)d_in[0];
  const float* ew     = (const float*)d_in[1];
  const float* Wgc    = (const float*)d_in[2];
  const float* bgc    = (const float*)d_in[3];
  const float* Wbi    = (const float*)d_in[4];
  const float* bbi    = (const float*)d_in[5];
  const int*   ei     = (const int*)d_in[6];
  const int*   users  = (const int*)d_in[7];
  const int*   pos    = (const int*)d_in[8];
  const int*   neg    = (const int*)d_in[9];
  float* out = (float*)d_out;

  // Workspace layout (4B units); 16B alignment holds for all int4 accesses.
  float* side = (float*)d_ws;                     // NN*DD
  float* ego  = side + (size_t)NN * DD;           // NN*DD
  float* norm = ego  + (size_t)NN * DD;           // NN*DD
  int*   base   = (int*)(norm + (size_t)NN * DD); // NN+4 (pad)
  int*   tiles  = base + (NN + 4);                // NTILE sums + NTILE offs
  int2*  edata  = (int2*)(tiles + 2 * ((NTILE + 1) & ~1)); // NE int2
  // rank[NE] aliases `side`: the CSR build completes before side is written.
  int*   rank = (int*)side;

  const dim3 blk(256);

  k_gather<<<dim3((3 * NB) / 4), blk, 0, stream>>>(embeds, users, pos, neg, out, 0);

  // CSR build
  hipMemsetAsync(base, 0, (size_t)(NN + 4) * sizeof(int), stream);
  k_count<<<dim3(4096), blk, 0, stream>>>(ei, base, rank);
  k_scan_part<<<dim3(NTILE), blk, 0, stream>>>(base, tiles);
  k_scan_tiles<<<dim3(1), dim3(128), 0, stream>>>(tiles, tiles + ((NTILE + 1) & ~1));
  k_scan_apply<<<dim3(NTILE), blk, 0, stream>>>(base, tiles + ((NTILE + 1) & ~1));
  k_permute<<<dim3(4096), blk, 0, stream>>>(ei, ew, base, rank, edata);

  const float* cur = embeds;
  for (int k = 0; k < 3; ++k) {
    k_aggregate<<<dim3(4096), blk, 0, stream>>>(cur, base, edata, side);
    k_update<<<dim3(2048), blk, 0, stream>>>(
        side, cur, ego, norm,
        Wgc + (size_t)k * DD * DD, bgc + (size_t)k * DD,
        Wbi + (size_t)k * DD * DD, bbi + (size_t)k * DD);
    k_gather<<<dim3((3 * NB) / 4), blk, 0, stream>>>(norm, users, pos, neg, out,
                                                     DD * (k + 1));
    cur = ego;
  }
}